// Round 3
// baseline (349.376 us; speedup 1.0000x reference)
//
#include <hip/hip_runtime.h>

typedef _Float16 f16;
typedef _Float16 f16x8 __attribute__((ext_vector_type(8)));
typedef _Float16 f16x4 __attribute__((ext_vector_type(4)));
typedef float f32x16 __attribute__((ext_vector_type(16)));
typedef float f32x4 __attribute__((ext_vector_type(4)));
typedef unsigned int u32;
typedef u32 u32x2 __attribute__((ext_vector_type(2)));
typedef u32 u32x4v __attribute__((ext_vector_type(4)));

#define MFMA_F16 __builtin_amdgcn_mfma_f32_32x32x16_f16

// x: (B=8, N=4096, C=64) fp32; out = gamma*softmax(qq^T)q + x
constexpr int N    = 4096;
constexpr int C    = 64;
constexpr int KV   = 64;            // keys per tile
constexpr int QB   = 128;           // queries per block
constexpr int NGRP = 4;             // kv-split groups per block
constexpr int NT4  = N / KV / NGRP; // 16 tiles per group
constexpr float LOG2E = 1.44269504088896f;
constexpr float THR   = 11.0f;      // defer-max threshold (log2 units)

__device__ __forceinline__ float fexp2(float x) { return __builtin_amdgcn_exp2f(x); }

__device__ __forceinline__ u32 pkrtz(float a, float b) {
    return __builtin_bit_cast(u32, __builtin_amdgcn_cvt_pkrtz(a, b));
}

// 8-byte-granule XOR swizzle within a 128-B row
__device__ __forceinline__ int swz8(int row, int bcol) {
    return row * 128 + (bcol ^ ((row & 15) << 3));
}

__device__ __forceinline__ f16x8 frag8(const char* base, int row, int bcol) {
    f16x4 lo = *(const f16x4*)(base + swz8(row, bcol));
    f16x4 hi = *(const f16x4*)(base + swz8(row, bcol + 8));
    return __builtin_shufflevector(lo, hi, 0, 1, 2, 3, 4, 5, 6, 7);
}

__global__ __launch_bounds__(1024, 4)
void channel_attn_kernel(const float* __restrict__ x,
                         const float* __restrict__ gamma,
                         float* __restrict__ out) {
    // staging: 4 groups x 2 bufs x (K 8KB + V^T 8KB) = 128 KB (all of smem)
    // post-loop reuse: pO [3][128][68]f32 @0 (104448 B), pm/pl @104448,
    //                  epilogue ep [64][33]f32 per q-wave @ qw*8448 (33792 B)
    __shared__ __align__(16) unsigned char smem[131072];

    const int tid = threadIdx.x;
    const int w   = tid >> 6;
    const int g   = w >> 2;            // kv group 0..3
    const int qw  = w & 3;             // q sub-tile 0..3
    const int l   = tid & 63;
    const int h   = l >> 5;
    const int q   = l & 31;
    const int bid = blockIdx.x;
    const int b   = bid & 7;           // XCD-affine: batch == XCD slot
    const int qt  = bid >> 3;
    const float* xb = x + (size_t)b * (N * C);
    const int qbase = qt * QB;
    const int qg   = qw * 32 + q;
    const int qrow = qbase + qg;

    // ---- Q fragments, pre-scaled by log2(e) ----
    f16x8 Qf[4];
    {
        const float* qs = xb + (size_t)qrow * C + h * 8;
        #pragma unroll
        for (int kk = 0; kk < 4; ++kk) {
            f32x4 a  = *(const f32x4*)(qs + kk * 16);
            f32x4 c2 = *(const f32x4*)(qs + kk * 16 + 4);
            f16x8 f;
            f[0] = (f16)(a[0] * LOG2E);  f[1] = (f16)(a[1] * LOG2E);
            f[2] = (f16)(a[2] * LOG2E);  f[3] = (f16)(a[3] * LOG2E);
            f[4] = (f16)(c2[0] * LOG2E); f[5] = (f16)(c2[1] * LOG2E);
            f[6] = (f16)(c2[2] * LOG2E); f[7] = (f16)(c2[3] * LOG2E);
            Qf[kk] = f;
        }
    }

    // ---- staging: lane owns a 4x4 (key x channel) block of the 64x64 tile ----
    const int c0  = (l & 15) * 4;            // channel start
    const int kr0 = qw * 16 + (l >> 4) * 4;  // key-row start within tile
    f32x4 stg[4];

    auto stage_load = [&](int kt) {
        const float* src = xb + ((size_t)((g * NT4 + kt) * KV + kr0) * C + c0);
        #pragma unroll
        for (int j = 0; j < 4; ++j) stg[j] = *(const f32x4*)(src + j * C);  // dwordx4
    };
    auto stage_write = [&](int sel) {
        char* kb = (char*)smem + g * 32768 + sel * 16384;  // K [key][c] f16
        char* vb = kb + 8192;                              // V^T [c][key] f16
        #pragma unroll
        for (int j = 0; j < 4; ++j) {
            u32x2 kv2 = { pkrtz(stg[j][0], stg[j][1]), pkrtz(stg[j][2], stg[j][3]) };
            *(u32x2*)(kb + swz8(kr0 + j, c0 * 2)) = kv2;
        }
        #pragma unroll
        for (int i = 0; i < 4; ++i) {   // in-reg 4x4 transpose -> V^T rows
            u32x2 vv = { pkrtz(stg[0][i], stg[1][i]), pkrtz(stg[2][i], stg[3][i]) };
            *(u32x2*)(vb + swz8(c0 + i, qw * 32 + (l >> 4) * 8)) = vv;
        }
    };

    f32x16 ot[2] = {};
    float m_run = -INFINITY, l_run = 0.f;

    stage_load(0);
    stage_write(0);
    __syncthreads();

    #pragma unroll 2
    for (int kt = 0; kt < NT4; ++kt) {
        const int sel = kt & 1;
        if (kt + 1 < NT4) stage_load(kt + 1);      // issue early (T14)

        const char* kb = (const char*)smem + g * 32768 + sel * 16384;
        const char* vb = kb + 8192;

        // ---- S'^T = K · (log2e·Q)^T ----
        f32x16 st[2];
        __builtin_amdgcn_s_setprio(1);
        #pragma unroll
        for (int n = 0; n < 2; ++n) {
            f32x16 acc = {};
            #pragma unroll
            for (int kk = 0; kk < 4; ++kk) {
                f16x8 kf = frag8(kb, q + 32 * n, kk * 32 + h * 16);
                acc = MFMA_F16(kf, Qf[kk], acc, 0, 0, 0);
            }
            st[n] = acc;
        }
        __builtin_amdgcn_s_setprio(0);

        // ---- online softmax (log2 domain), tree reduce ----
        float mx[4];
        #pragma unroll
        for (int t = 0; t < 4; ++t) mx[t] = fmaxf(st[0][t], st[1][t]);
        #pragma unroll
        for (int r2 = 4; r2 < 16; r2 += 4)
            #pragma unroll
            for (int t = 0; t < 4; ++t)
                mx[t] = fmaxf(mx[t], fmaxf(st[0][r2 + t], st[1][r2 + t]));
        float pmax = fmaxf(fmaxf(mx[0], mx[1]), fmaxf(mx[2], mx[3]));
        pmax = fmaxf(pmax, __shfl_xor(pmax, 32, 64));

        if (!__all(pmax - m_run <= THR)) {          // defer-max (T13)
            float m_new = fmaxf(m_run, pmax);
            float scf = fexp2(m_run - m_new);
            l_run *= scf;
            #pragma unroll
            for (int mI = 0; mI < 2; ++mI)
                #pragma unroll
                for (int r2 = 0; r2 < 16; ++r2) ot[mI][r2] *= scf;
            m_run = m_new;
        }

        float rs4[4] = {0.f, 0.f, 0.f, 0.f};
        #pragma unroll
        for (int n = 0; n < 2; ++n)
            #pragma unroll
            for (int r2 = 0; r2 < 16; ++r2) {
                float p = fexp2(st[n][r2] - m_run);
                st[n][r2] = p;
                rs4[r2 & 3] += p;
            }
        float rs = (rs4[0] + rs4[1]) + (rs4[2] + rs4[3]);
        rs += __shfl_xor(rs, 32, 64);
        l_run += rs;

        // ---- P^T -> f16 B-fragments (pkrtz + cross-half exchange) ----
        f16x8 Pf[4];
        #pragma unroll
        for (int kk = 0; kk < 4; ++kk) {
            int n  = kk >> 1;
            int so = 2 * (kk & 1) + h;
            int sx = 2 * (kk & 1) + (1 - h);
            u32 ua0 = pkrtz(st[n][so*4+0], st[n][so*4+1]);
            u32 ua1 = pkrtz(st[n][so*4+2], st[n][so*4+3]);
            u32 ub0 = pkrtz(st[n][sx*4+0], st[n][sx*4+1]);
            u32 ub1 = pkrtz(st[n][sx*4+2], st[n][sx*4+3]);
            u32 r0 = __shfl_xor(ub0, 32, 64);
            u32 r1 = __shfl_xor(ub1, 32, 64);
            u32x4v uv;
            uv[0] = h ? r0 : ua0;
            uv[1] = h ? r1 : ua1;
            uv[2] = h ? ua0 : r0;
            uv[3] = h ? ua1 : r1;
            Pf[kk] = __builtin_bit_cast(f16x8, uv);
        }

        if (kt + 1 < NT4) stage_write(sel ^ 1);     // consume loads late

        // ---- O^T += V^T · P^T ----
        __builtin_amdgcn_s_setprio(1);
        #pragma unroll
        for (int mI = 0; mI < 2; ++mI) {
            f32x16 acc = ot[mI];
            #pragma unroll
            for (int kk = 0; kk < 4; ++kk) {
                f16x8 vf = frag8(vb, q + 32 * mI, kk * 32 + h * 16);
                acc = MFMA_F16(vf, Pf[kk], acc, 0, 0, 0);
            }
            ot[mI] = acc;
        }
        __builtin_amdgcn_s_setprio(0);

        __syncthreads();
    }

    // ---- intra-block flash-decoding merge of the 4 kv-group partials ----
    float* pO = (float*)smem;                       // [3][128][68]
    float* pm = (float*)(smem + 104448);            // [3][128]
    float* pl = pm + 384;

    if (g > 0) {
        float* po = pO + (size_t)(g - 1) * (128 * 68) + qg * 68;
        #pragma unroll
        for (int mI = 0; mI < 2; ++mI)
            #pragma unroll
            for (int j = 0; j < 4; ++j) {
                f32x4 v = { ot[mI][4*j], ot[mI][4*j+1], ot[mI][4*j+2], ot[mI][4*j+3] };
                *(f32x4*)(po + mI * 32 + j * 8 + h * 4) = v;   // c = 32mI+8j+4h+0..3
            }
        if (h == 0) { pm[(g - 1) * 128 + qg] = m_run; pl[(g - 1) * 128 + qg] = l_run; }
    }
    __syncthreads();

    float L = 1.0f;
    if (g == 0) {
        float m1 = pm[qg], m2 = pm[128 + qg], m3 = pm[256 + qg];
        float l1 = pl[qg], l2 = pl[128 + qg], l3 = pl[256 + qg];
        float M  = fmaxf(fmaxf(m_run, m1), fmaxf(m2, m3));
        float a0 = fexp2(m_run - M);
        float ag[3] = { fexp2(m1 - M), fexp2(m2 - M), fexp2(m3 - M) };
        L = l_run * a0 + l1 * ag[0] + l2 * ag[1] + l3 * ag[2];
        #pragma unroll
        for (int mI = 0; mI < 2; ++mI)
            #pragma unroll
            for (int r2 = 0; r2 < 16; ++r2) ot[mI][r2] *= a0;
        #pragma unroll
        for (int gg = 0; gg < 3; ++gg) {
            const float* po = pO + (size_t)gg * (128 * 68) + qg * 68;
            #pragma unroll
            for (int mI = 0; mI < 2; ++mI)
                #pragma unroll
                for (int j = 0; j < 4; ++j) {
                    f32x4 v = *(const f32x4*)(po + mI * 32 + j * 8 + h * 4);
                    ot[mI][4*j+0] += ag[gg] * v[0];
                    ot[mI][4*j+1] += ag[gg] * v[1];
                    ot[mI][4*j+2] += ag[gg] * v[2];
                    ot[mI][4*j+3] += ag[gg] * v[3];
                }
        }
    }
    __syncthreads();   // all waves: pO reads done before ep overwrites region

    if (g == 0) {
        float invl = 1.0f / L;
        float* ep = (float*)(smem + qw * 8448);     // [64][33] per q-wave
        #pragma unroll
        for (int mI = 0; mI < 2; ++mI)
            #pragma unroll
            for (int r2 = 0; r2 < 16; ++r2) {
                int c = 32 * mI + (r2 & 3) + 8 * (r2 >> 2) + 4 * h;
                ep[c * 33 + q] = ot[mI][r2] * invl;
            }

        const float gm = gamma[0];
        float* ob = out + (size_t)b * (N * C);
        #pragma unroll
        for (int it = 0; it < 8; ++it) {
            int ql  = it * 4 + (l >> 4);
            int cc0 = (l & 15) * 4;
            f32x4 o;
            o[0] = ep[(cc0 + 0) * 33 + ql];
            o[1] = ep[(cc0 + 1) * 33 + ql];
            o[2] = ep[(cc0 + 2) * 33 + ql];
            o[3] = ep[(cc0 + 3) * 33 + ql];
            int row = qbase + qw * 32 + ql;
            f32x4 xi = *(const f32x4*)(xb + (size_t)row * C + cc0);
            f32x4 res = { gm * o[0] + xi[0], gm * o[1] + xi[1],
                          gm * o[2] + xi[2], gm * o[3] + xi[3] };
            *(f32x4*)(ob + (size_t)row * C + cc0) = res;
        }
    }
}

extern "C" void kernel_launch(void* const* d_in, const int* in_sizes, int n_in,
                              void* d_out, int out_size, void* d_ws, size_t ws_size,
                              hipStream_t stream) {
    const float* x     = (const float*)d_in[0];
    const float* gamma = (const float*)d_in[1];
    float* out         = (float*)d_out;
    dim3 grid(256), block(1024);
    channel_attn_kernel<<<grid, block, 0, stream>>>(x, gamma, out);
}

// Round 4
// 203.698 us; speedup vs baseline: 1.7152x; 1.7152x over previous
//
#include <hip/hip_runtime.h>

typedef _Float16 f16;
typedef _Float16 f16x4 __attribute__((ext_vector_type(4)));
typedef _Float16 f16x8 __attribute__((ext_vector_type(8)));
typedef float f32x4 __attribute__((ext_vector_type(4)));
typedef float f32x16 __attribute__((ext_vector_type(16)));
typedef unsigned int u32;
typedef u32 u32x2 __attribute__((ext_vector_type(2)));
typedef u32 u32x4v __attribute__((ext_vector_type(4)));

#define MFMA_F16 __builtin_amdgcn_mfma_f32_32x32x16_f16

// x: (B=8, N=4096, C=64) fp32; out = gamma*softmax(qq^T)q + x
constexpr int N   = 4096;
constexpr int C   = 64;
constexpr int KV  = 32;                 // keys per tile
constexpr int QB  = 64;                 // queries per block (2 waves x 32)
constexpr int NGRP = 4;                 // kv-split groups per block
constexpr int KEYS_PER_GRP = N / NGRP;  // 1024
constexpr int NT  = KEYS_PER_GRP / KV;  // 32 iters
constexpr float LOG2E = 1.44269504088896f;
constexpr float THR   = 11.0f;          // defer-max threshold (log2 units)

// LDS staging layout (padded rows -> conflict-free-ish AND immediate-foldable)
constexpr int KROW    = 136;            // 64 ch * 2B + 8 pad
constexpr int VROW    = 72;             // 32 keys * 2B + 8 pad
constexpr int VOFF    = 32 * KROW;      // 4352
constexpr int BUFSZ   = VOFF + 64 * VROW;   // 8960
constexpr int GSTRIDE = 2 * BUFSZ;      // 17920 per group; x4 = 71680
// merge region (overlays staging after the loop)
constexpr int PM_OFF  = 52224;          // pO [3][64][68] f32 = 52224 B at 0
constexpr int PL_OFF  = PM_OFF + 768;   // pm/pl [3][64] f32 each
constexpr int EP_OFF  = 53760;          // ep [64][33] f32 per q-wave (+qw*8448)

__device__ __forceinline__ float fexp2(float x) { return __builtin_amdgcn_exp2f(x); }
__device__ __forceinline__ u32 pkrtz(float a, float b) {
    return __builtin_bit_cast(u32, __builtin_amdgcn_cvt_pkrtz(a, b));
}
__device__ __forceinline__ f16x8 ld8(const char* p) {   // 8-B aligned, 2x ds_read_b64
    f16x4 lo = *(const f16x4*)p;
    f16x4 hi = *(const f16x4*)(p + 8);
    return __builtin_shufflevector(lo, hi, 0, 1, 2, 3, 4, 5, 6, 7);
}

__global__ __launch_bounds__(512, 4)
void channel_attn_kernel(const float* __restrict__ x,
                         const float* __restrict__ gamma,
                         float* __restrict__ out) {
    __shared__ __align__(16) unsigned char smem[71680];

    const int tid = threadIdx.x;
    const int w   = tid >> 6;
    const int g   = w >> 1;             // kv group 0..3
    const int qw  = w & 1;              // q sub-tile 0..1
    const int l   = tid & 63;
    const int h   = l >> 5;
    const int q   = l & 31;             // A-row / B-col index (key or query)
    const int bid = blockIdx.x;
    const int b   = bid & 7;            // XCD-affine: batch == XCD slot
    const int qt  = bid >> 3;           // q-tile 0..63
    const float* xb = x + (size_t)b * (N * C);
    const int qbase = qt * QB;
    const int qg   = qw * 32 + q;
    const int qrow = qbase + qg;

    // ---- Q fragments, pre-scaled by log2(e) (exp2-domain softmax) ----
    f16x8 Qf[4];
    {
        const float* qs = xb + (size_t)qrow * C + h * 8;
        #pragma unroll
        for (int kk = 0; kk < 4; ++kk) {
            f32x4 a  = *(const f32x4*)(qs + kk * 16);
            f32x4 c2 = *(const f32x4*)(qs + kk * 16 + 4);
            f16x8 f;
            f[0] = (f16)(a[0] * LOG2E);  f[1] = (f16)(a[1] * LOG2E);
            f[2] = (f16)(a[2] * LOG2E);  f[3] = (f16)(a[3] * LOG2E);
            f[4] = (f16)(c2[0] * LOG2E); f[5] = (f16)(c2[1] * LOG2E);
            f[6] = (f16)(c2[2] * LOG2E); f[7] = (f16)(c2[3] * LOG2E);
            Qf[kk] = f;
        }
    }

    // ---- staging: lane owns 4 keys x 4 channels of the 32x64 tile ----
    const int c0  = (l & 15) * 4;            // channel start
    const int kr0 = qw * 16 + (l >> 4) * 4;  // key row start (0..28)
    f32x4 stg[4];
    char* gb = (char*)smem + g * GSTRIDE;

    const float* kvsrc = xb + ((size_t)(g * KEYS_PER_GRP + kr0) * C + c0);

    auto stage_load = [&]() {
        #pragma unroll
        for (int j = 0; j < 4; ++j) stg[j] = *(const f32x4*)(kvsrc + j * C);
        kvsrc += KV * C;
    };
    auto stage_write = [&](int sel) {
        char* kb = gb + sel * BUFSZ;             // K [key][ch] f16, 136 B rows
        char* vb = kb + VOFF;                    // V^T [ch][key] f16, 72 B rows
        #pragma unroll
        for (int j = 0; j < 4; ++j) {
            u32x2 kv2 = { pkrtz(stg[j][0], stg[j][1]), pkrtz(stg[j][2], stg[j][3]) };
            *(u32x2*)(kb + (kr0 + j) * KROW + c0 * 2) = kv2;
        }
        #pragma unroll
        for (int i = 0; i < 4; ++i) {            // in-reg 4x4 transpose
            u32x2 vv = { pkrtz(stg[0][i], stg[1][i]), pkrtz(stg[2][i], stg[3][i]) };
            *(u32x2*)(vb + (c0 + i) * VROW + kr0 * 2) = vv;
        }
    };

    f32x16 ot[2] = {};                  // O^T accum: ch (2x32) x query
    float m_run = -INFINITY, l_run = 0.f;

    stage_load();
    stage_write(0);
    __syncthreads();

    #pragma unroll 2
    for (int kt = 0; kt < NT; ++kt) {
        const int sel = kt & 1;
        const char* kb = gb + sel * BUFSZ;
        const char* vb = kb + VOFF;

        if (kt + 1 < NT) stage_load();          // issue early (T14)

        // ---- S'^T = K · (log2e·Q)^T : 32 keys x 32 queries ----
        f32x16 st = {};
        __builtin_amdgcn_s_setprio(1);
        #pragma unroll
        for (int kk = 0; kk < 4; ++kk) {
            f16x8 kf = ld8(kb + q * KROW + h * 16 + kk * 32);
            st = MFMA_F16(kf, Qf[kk], st, 0, 0, 0);
        }
        __builtin_amdgcn_s_setprio(0);

        // ---- online softmax (log2 domain) ----
        float m01 = fmaxf(st[0], st[1]),  m23 = fmaxf(st[2], st[3]);
        float m45 = fmaxf(st[4], st[5]),  m67 = fmaxf(st[6], st[7]);
        float m89 = fmaxf(st[8], st[9]),  mab = fmaxf(st[10], st[11]);
        float mcd = fmaxf(st[12], st[13]), mef = fmaxf(st[14], st[15]);
        float pmax = fmaxf(fmaxf(fmaxf(m01, m23), fmaxf(m45, m67)),
                           fmaxf(fmaxf(m89, mab), fmaxf(mcd, mef)));
        pmax = fmaxf(pmax, __shfl_xor(pmax, 32, 64));

        if (!__all(pmax - m_run <= THR)) {       // defer-max (T13)
            float m_new = fmaxf(m_run, pmax);
            float scf = fexp2(m_run - m_new);
            l_run *= scf;
            #pragma unroll
            for (int mI = 0; mI < 2; ++mI)
                #pragma unroll
                for (int r2 = 0; r2 < 16; ++r2) ot[mI][r2] *= scf;
            m_run = m_new;
        }

        float rs4[4] = {0.f, 0.f, 0.f, 0.f};
        #pragma unroll
        for (int r2 = 0; r2 < 16; ++r2) {
            float p = fexp2(st[r2] - m_run);
            st[r2] = p;
            rs4[r2 & 3] += p;
        }
        float rs = (rs4[0] + rs4[1]) + (rs4[2] + rs4[3]);
        rs += __shfl_xor(rs, 32, 64);
        l_run += rs;

        // ---- P^T -> f16 B-fragments (pkrtz + cross-half exchange) ----
        // st[r2] holds key = (r2&3) + 8*(r2>>2) + 4h; frag kk needs keys 16kk+8h+j
        f16x8 Pf[2];
        #pragma unroll
        for (int kk = 0; kk < 2; ++kk) {
            int so = 2 * kk + h;                 // s-slot I need
            int sx = 2 * kk + (1 - h);           // s-slot my partner needs
            u32 ua0 = pkrtz(st[so*4+0], st[so*4+1]);
            u32 ua1 = pkrtz(st[so*4+2], st[so*4+3]);
            u32 ub0 = pkrtz(st[sx*4+0], st[sx*4+1]);
            u32 ub1 = pkrtz(st[sx*4+2], st[sx*4+3]);
            u32 r0 = __shfl_xor(ub0, 32, 64);
            u32 r1 = __shfl_xor(ub1, 32, 64);
            u32x4v uv;
            uv[0] = h ? r0 : ua0;                // j=0..3 from h_src=0
            uv[1] = h ? r1 : ua1;
            uv[2] = h ? ua0 : r0;                // j=4..7 from h_src=1
            uv[3] = h ? ua1 : r1;
            Pf[kk] = __builtin_bit_cast(f16x8, uv);
        }

        if (kt + 1 < NT) stage_write(sel ^ 1);   // consume loads late

        // ---- O^T += V^T · P^T ----
        __builtin_amdgcn_s_setprio(1);
        #pragma unroll
        for (int mI = 0; mI < 2; ++mI) {
            f32x16 acc = ot[mI];
            #pragma unroll
            for (int kk = 0; kk < 2; ++kk) {
                f16x8 vf = ld8(vb + (q + 32 * mI) * VROW + h * 16 + kk * 32);
                acc = MFMA_F16(vf, Pf[kk], acc, 0, 0, 0);
            }
            ot[mI] = acc;
        }
        __builtin_amdgcn_s_setprio(0);

        __syncthreads();
    }

    // ---- intra-block flash-decoding merge of the 4 kv-group partials ----
    float* pO = (float*)smem;                    // [3][64][68]
    float* pm = (float*)(smem + PM_OFF);         // [3][64]
    float* pl = (float*)(smem + PL_OFF);         // [3][64]

    if (g > 0) {
        float* po = pO + (size_t)(g - 1) * (64 * 68) + qg * 68;
        #pragma unroll
        for (int mI = 0; mI < 2; ++mI)
            #pragma unroll
            for (int j = 0; j < 4; ++j) {
                f32x4 v = { ot[mI][4*j], ot[mI][4*j+1], ot[mI][4*j+2], ot[mI][4*j+3] };
                *(f32x4*)(po + mI * 32 + j * 8 + h * 4) = v;   // c = 32mI+8j+4h+t
            }
        if (h == 0) { pm[(g - 1) * 64 + qg] = m_run; pl[(g - 1) * 64 + qg] = l_run; }
    }
    __syncthreads();

    if (g == 0) {
        float m1 = pm[qg], m2 = pm[64 + qg], m3 = pm[128 + qg];
        float l1 = pl[qg], l2 = pl[64 + qg], l3 = pl[128 + qg];
        float M  = fmaxf(fmaxf(m_run, m1), fmaxf(m2, m3));
        float a0 = fexp2(m_run - M);
        float ag[3] = { fexp2(m1 - M), fexp2(m2 - M), fexp2(m3 - M) };
        float L = l_run * a0 + l1 * ag[0] + l2 * ag[1] + l3 * ag[2];
        #pragma unroll
        for (int mI = 0; mI < 2; ++mI)
            #pragma unroll
            for (int r2 = 0; r2 < 16; ++r2) ot[mI][r2] *= a0;
        #pragma unroll
        for (int gg = 0; gg < 3; ++gg) {
            const float* po = pO + (size_t)gg * (64 * 68) + qg * 68;
            #pragma unroll
            for (int mI = 0; mI < 2; ++mI)
                #pragma unroll
                for (int j = 0; j < 4; ++j) {
                    f32x4 v = *(const f32x4*)(po + mI * 32 + j * 8 + h * 4);
                    ot[mI][4*j+0] += ag[gg] * v[0];
                    ot[mI][4*j+1] += ag[gg] * v[1];
                    ot[mI][4*j+2] += ag[gg] * v[2];
                    ot[mI][4*j+3] += ag[gg] * v[3];
                }
        }

        float invl = 1.0f / L;
        float* ep = (float*)(smem + EP_OFF + qw * 8448);   // [64][33] per q-wave
        #pragma unroll
        for (int mI = 0; mI < 2; ++mI)
            #pragma unroll
            for (int r2 = 0; r2 < 16; ++r2) {
                int c = 32 * mI + (r2 & 3) + 8 * (r2 >> 2) + 4 * h;
                ep[c * 33 + q] = ot[mI][r2] * invl;
            }

        const float gm = gamma[0];
        float* ob = out + (size_t)b * (N * C);
        #pragma unroll
        for (int it = 0; it < 8; ++it) {
            int ql  = it * 4 + (l >> 4);
            int cc0 = (l & 15) * 4;
            f32x4 o;
            o[0] = ep[(cc0 + 0) * 33 + ql];
            o[1] = ep[(cc0 + 1) * 33 + ql];
            o[2] = ep[(cc0 + 2) * 33 + ql];
            o[3] = ep[(cc0 + 3) * 33 + ql];
            int row = qbase + qw * 32 + ql;
            f32x4 xi = *(const f32x4*)(xb + (size_t)row * C + cc0);
            f32x4 res = { gm * o[0] + xi[0], gm * o[1] + xi[1],
                          gm * o[2] + xi[2], gm * o[3] + xi[3] };
            *(f32x4*)(ob + (size_t)row * C + cc0) = res;
        }
    }
}

extern "C" void kernel_launch(void* const* d_in, const int* in_sizes, int n_in,
                              void* d_out, int out_size, void* d_ws, size_t ws_size,
                              hipStream_t stream) {
    const float* x     = (const float*)d_in[0];
    const float* gamma = (const float*)d_in[1];
    float* out         = (float*)d_out;
    dim3 grid(512), block(512);
    channel_attn_kernel<<<grid, block, 0, stream>>>(x, gamma, out);
}